// Round 1
// baseline (608.365 us; speedup 1.0000x reference)
//
#include <hip/hip_runtime.h>
#include <hip/hip_bf16.h>

// N = 1048576 rows, DIN=128 (4 arrays of 32 fp32), DOUT=64.
// Key reduction: graph only couples rows 0..3; rows >=4 are out = MLP(x_row),
// rows 0..3 are out = MLP(mean(x_0..3)) broadcast. Main kernel = streaming
// bf16-MFMA MLP over all rows; tiny fixup kernel overwrites rows 0..3.

typedef __bf16 bf16x8 __attribute__((ext_vector_type(8)));
typedef float  f32x4  __attribute__((ext_vector_type(4)));

__device__ __forceinline__ float4 ld4(const float* p) { return *(const float4*)p; }

__device__ __forceinline__ bf16x8 cvt8(float4 a, float4 b) {
  bf16x8 r;
  r[0] = (__bf16)a.x; r[1] = (__bf16)a.y; r[2] = (__bf16)a.z; r[3] = (__bf16)a.w;
  r[4] = (__bf16)b.x; r[5] = (__bf16)b.y; r[6] = (__bf16)b.z; r[7] = (__bf16)b.w;
  return r;
}

// LDS strides (bf16 units). 136 = 128+8 pad, 72 = 64+8 pad: keep b128 reads
// 16B-aligned (stride % 8 == 0) and spread banks (no >=4-way conflicts).
#define XSTRIDE 136
#define GSTRIDE 72

__global__ __launch_bounds__(256, 2)
void gcn_main(const float* __restrict__ a0, const float* __restrict__ a1,
              const float* __restrict__ a2, const float* __restrict__ a3,
              const float* __restrict__ W1, const float* __restrict__ b1,
              const float* __restrict__ W2, const float* __restrict__ b2,
              float* __restrict__ out, int ntiles)
{
  const int lane = threadIdx.x & 63;
  const int wib  = threadIdx.x >> 6;      // wave in block (0..3)
  const int m    = lane & 15;             // mfma "lane&15" index
  const int q    = lane >> 4;             // quad (0..3)
  const int gw   = blockIdx.x * 4 + wib;  // global wave id
  const int nw   = gridDim.x * 4;

  __shared__ __bf16 xlds_all[4][16 * XSTRIDE]; // per-wave x tile (16 rows x 128 bf16)
  __shared__ __bf16 glds_all[4][16 * GSTRIDE]; // per-wave g tile (16 rows x 64 bf16)
  __bf16* xlds = xlds_all[wib];
  __bf16* glds = glds_all[wib];

  // --- Weight fragments in registers (B-operand layout: n = lane&15, k = q*8+j).
  // B[k][n] = Wx[n][k] -> 8 contiguous fp32 from the row-major weight row.
  bf16x8 wf1[4][4]; // [ntile][kstep]  W1: 64x128
#pragma unroll
  for (int nt = 0; nt < 4; ++nt)
#pragma unroll
    for (int s = 0; s < 4; ++s) {
      const float* p = W1 + (nt * 16 + m) * 128 + s * 32 + q * 8;
      wf1[nt][s] = cvt8(ld4(p), ld4(p + 4));
    }
  bf16x8 wf2[4][2]; // W2: 64x64
#pragma unroll
  for (int nt = 0; nt < 4; ++nt)
#pragma unroll
    for (int s = 0; s < 2; ++s) {
      const float* p = W2 + (nt * 16 + m) * 64 + s * 32 + q * 8;
      wf2[nt][s] = cvt8(ld4(p), ld4(p + 4));
    }
  float b1v[4], b2v[4];
#pragma unroll
  for (int nt = 0; nt < 4; ++nt) {
    b1v[nt] = b1[nt * 16 + m];
    b2v[nt] = b2[nt * 16 + m];
  }

  const float* arrs[4] = {a0, a1, a2, a3};
  // Staging assignment: lane covers row lane>>2, 8 floats at col (lane&3)*8
  // of each 16x32 fp32 block -> dwordx4 loads fully coalesced.
  const int srow = lane >> 2;
  const int scol = (lane & 3) * 8;

  for (int t = gw; t < ntiles; t += nw) {
    const int rowbase = t * 16;

    // ---- Stage x tile: global fp32 (coalesced) -> bf16 in LDS
#pragma unroll
    for (int s = 0; s < 4; ++s) {
      const float* p = arrs[s] + (size_t)(rowbase + srow) * 32 + scol;
      float4 u = ld4(p), v = ld4(p + 4);
      *(bf16x8*)(xlds + srow * XSTRIDE + s * 32 + scol) = cvt8(u, v);
    }
    __syncthreads(); // make cross-lane LDS writes visible

    // ---- Layer 1: h = x @ W1^T   (M=16, N=64, K=128)
    f32x4 zero4 = {0.f, 0.f, 0.f, 0.f};
    f32x4 acc[4] = {zero4, zero4, zero4, zero4};
#pragma unroll
    for (int s = 0; s < 4; ++s) {
      bf16x8 af = *(const bf16x8*)(xlds + m * XSTRIDE + s * 32 + q * 8);
#pragma unroll
      for (int nt = 0; nt < 4; ++nt)
        acc[nt] = __builtin_amdgcn_mfma_f32_16x16x32_bf16(af, wf1[nt][s], acc[nt], 0, 0, 0);
    }

    // ---- g = relu(h + b1) -> LDS (C/D layout: row=q*4+i, col=nt*16+m)
#pragma unroll
    for (int nt = 0; nt < 4; ++nt)
#pragma unroll
      for (int i = 0; i < 4; ++i) {
        float v = fmaxf(acc[nt][i] + b1v[nt], 0.f);
        glds[(q * 4 + i) * GSTRIDE + nt * 16 + m] = (__bf16)v;
      }
    __syncthreads();

    // ---- Layer 2: out = g @ W2^T  (M=16, N=64, K=64)
    f32x4 acc2[4] = {zero4, zero4, zero4, zero4};
#pragma unroll
    for (int s = 0; s < 2; ++s) {
      bf16x8 gf = *(const bf16x8*)(glds + m * GSTRIDE + s * 32 + q * 8);
#pragma unroll
      for (int nt = 0; nt < 4; ++nt)
        acc2[nt] = __builtin_amdgcn_mfma_f32_16x16x32_bf16(gf, wf2[nt][s], acc2[nt], 0, 0, 0);
    }

    // ---- Epilogue: out[row][col] = acc2 + b2
    float* orow = out + (size_t)rowbase * 64;
#pragma unroll
    for (int nt = 0; nt < 4; ++nt)
#pragma unroll
      for (int i = 0; i < 4; ++i)
        orow[(q * 4 + i) * 64 + nt * 16 + m] = acc2[nt][i] + b2v[nt];
  }
}

// Rows 0..3: out = MLP(mean(x rows 0..3)), exact fp32, broadcast to 4 rows.
__global__ void gcn_fixup(const float* __restrict__ a0, const float* __restrict__ a1,
                          const float* __restrict__ a2, const float* __restrict__ a3,
                          const float* __restrict__ W1, const float* __restrict__ b1,
                          const float* __restrict__ W2, const float* __restrict__ b2,
                          float* __restrict__ out)
{
  const int t = threadIdx.x; // 64 threads
  __shared__ float xm[128];
  __shared__ float g[64];
  for (int e = t; e < 128; e += 64) {
    const float* arr = (e < 32) ? a0 : (e < 64) ? a1 : (e < 96) ? a2 : a3;
    int c = e & 31;
    xm[e] = 0.25f * (arr[c] + arr[32 + c] + arr[64 + c] + arr[96 + c]);
  }
  __syncthreads();
  float h = b1[t];
  for (int k = 0; k < 128; ++k) h += xm[k] * W1[t * 128 + k];
  g[t] = fmaxf(h, 0.f);
  __syncthreads();
  float o = b2[t];
  for (int j = 0; j < 64; ++j) o += g[j] * W2[t * 64 + j];
  for (int r = 0; r < 4; ++r) out[r * 64 + t] = o;
}

extern "C" void kernel_launch(void* const* d_in, const int* in_sizes, int n_in,
                              void* d_out, int out_size, void* d_ws, size_t ws_size,
                              hipStream_t stream) {
  const float* a0 = (const float*)d_in[0];
  const float* a1 = (const float*)d_in[1];
  const float* a2 = (const float*)d_in[2];
  const float* a3 = (const float*)d_in[3];
  const float* W1 = (const float*)d_in[4];
  const float* b1 = (const float*)d_in[5];
  const float* W2 = (const float*)d_in[6];
  const float* b2 = (const float*)d_in[7];
  float* out = (float*)d_out;

  const int n = in_sizes[0] / 32;   // rows
  const int ntiles = n / 16;        // 65536

  gcn_main<<<512, 256, 0, stream>>>(a0, a1, a2, a3, W1, b1, W2, b2, out, ntiles);
  gcn_fixup<<<1, 64, 0, stream>>>(a0, a1, a2, a3, W1, b1, W2, b2, out);
}